// Round 2
// baseline (978.762 us; speedup 1.0000x reference)
//
#include <hip/hip_runtime.h>

// Problem constants
#define Bsz 4
#define SQ 4096
#define SK 4096
#define DMODEL 1024
#define DKk 64
#define QSPLIT 8
#define SSPLIT 2

// Workspace layout (float offsets). Total = 5,390,336 floats ~= 20.6 MiB.
#define OFF_Q   ((size_t)0)
#define OFF_K   ((size_t)(1 << 20))
#define OFF_V   ((size_t)(2 << 20))
#define OFF_PL  ((size_t)(3 << 20))                       // QSPLIT * Bsz * SK = 131072
#define OFF_LI  (OFF_PL + (size_t)QSPLIT * Bsz * SK)      // Bsz * SK = 16384
#define OFF_YP  (OFF_LI + (size_t)Bsz * SK)               // SSPLIT * Bsz * SQ * DKk = 2097152

__device__ __forceinline__ void fma_4x4(float acc[4][4], const float4 a, const float4 b) {
    const float av[4] = {a.x, a.y, a.z, a.w};
    const float bv[4] = {b.x, b.y, b.z, b.w};
#pragma unroll
    for (int i = 0; i < 4; ++i)
#pragma unroll
        for (int j = 0; j < 4; ++j)
            acc[i][j] = fmaf(av[i], bv[j], acc[i][j]);
}

__device__ __forceinline__ void fma_8x8(float acc[8][8], const float4 a0, const float4 a1,
                                        const float4 b0, const float4 b1) {
    const float av[8] = {a0.x, a0.y, a0.z, a0.w, a1.x, a1.y, a1.z, a1.w};
    const float bv[8] = {b0.x, b0.y, b0.z, b0.w, b1.x, b1.y, b1.z, b1.w};
#pragma unroll
    for (int i = 0; i < 8; ++i)
#pragma unroll
        for (int j = 0; j < 8; ++j)
            acc[i][j] = fmaf(av[i], bv[j], acc[i][j]);
}

// ---------------------------------------------------------------------------
// K1: QKV projection. out = (x @ W^T + b), Q additionally prescaled by 1/8
// (exact pow-2, folds the 1/sqrt(d_k) into Q once).
// Tile: 128 rows x 64 cols, 128 threads, 8x8 per thread, KC=32.
// grid (16384/128, 3)
// ---------------------------------------------------------------------------
__global__ __launch_bounds__(128) void k_proj(
    const float* __restrict__ xq, const float* __restrict__ xk, const float* __restrict__ xv,
    const float* __restrict__ Wq, const float* __restrict__ bq,
    const float* __restrict__ Wk, const float* __restrict__ bk,
    const float* __restrict__ Wv, const float* __restrict__ bv,
    float* __restrict__ ws)
{
    __shared__ float xT[32][132];  // [k][row], padded: 16B-aligned rows, 2-4 way max
    __shared__ float wT[32][68];   // [k][col]

    const int t = threadIdx.x;
    const int which = blockIdx.y;
    const float* x    = which == 0 ? xq : (which == 1 ? xk : xv);
    const float* W    = which == 0 ? Wq : (which == 1 ? Wk : Wv);
    const float* bias = which == 0 ? bq : (which == 1 ? bk : bv);
    float* out = ws + (which == 0 ? OFF_Q : (which == 1 ? OFF_K : OFF_V));
    const float scale = (which == 0) ? 0.125f : 1.0f;

    const int row0 = blockIdx.x * 128;
    const int tx = t & 7;    // col group: cols 8*tx .. 8*tx+7
    const int ty = t >> 3;   // row group: rows 8*ty .. 8*ty+7

    float acc[8][8];
#pragma unroll
    for (int i = 0; i < 8; ++i)
#pragma unroll
        for (int j = 0; j < 8; ++j) acc[i][j] = 0.0f;

    for (int kc = 0; kc < DMODEL; kc += 32) {
        // stage x: 128 rows x 32 k, transposed
#pragma unroll
        for (int i = 0; i < 8; ++i) {
            const int flat = t + 128 * i;          // 0..1023
            const int r = flat >> 3, k4 = flat & 7;
            const float4 v = *(const float4*)(x + (size_t)(row0 + r) * DMODEL + kc + 4 * k4);
            xT[4 * k4 + 0][r] = v.x; xT[4 * k4 + 1][r] = v.y;
            xT[4 * k4 + 2][r] = v.z; xT[4 * k4 + 3][r] = v.w;
        }
        // stage W: 64 cols x 32 k, transposed
#pragma unroll
        for (int i = 0; i < 4; ++i) {
            const int flat = t + 128 * i;          // 0..511
            const int c = flat >> 3, k4 = flat & 7;
            const float4 v = *(const float4*)(W + (size_t)c * DMODEL + kc + 4 * k4);
            wT[4 * k4 + 0][c] = v.x; wT[4 * k4 + 1][c] = v.y;
            wT[4 * k4 + 2][c] = v.z; wT[4 * k4 + 3][c] = v.w;
        }
        __syncthreads();
#pragma unroll 4
        for (int k = 0; k < 32; ++k) {
            const float4 a0 = *(const float4*)&xT[k][8 * ty];
            const float4 a1 = *(const float4*)&xT[k][8 * ty + 4];
            const float4 b0 = *(const float4*)&wT[k][8 * tx];
            const float4 b1 = *(const float4*)&wT[k][8 * tx + 4];
            fma_8x8(acc, a0, a1, b0, b1);
        }
        __syncthreads();
    }

    float bb[8];
#pragma unroll
    for (int j = 0; j < 8; ++j) bb[j] = bias[8 * tx + j];
#pragma unroll
    for (int i = 0; i < 8; ++i) {
        const size_t r = (size_t)row0 + 8 * ty + i;
        float o[8];
#pragma unroll
        for (int j = 0; j < 8; ++j) o[j] = (acc[i][j] + bb[j]) * scale;
        *(float4*)(out + r * DKk + 8 * tx)     = make_float4(o[0], o[1], o[2], o[3]);
        *(float4*)(out + r * DKk + 8 * tx + 4) = make_float4(o[4], o[5], o[6], o[7]);
    }
}

// ---------------------------------------------------------------------------
// K2: column sums l[s] = sum_q mask * exp(S[q,s]). Q is prescaled, so
// S = qT . kT directly. Each block: 64 s-cols, 512 q-rows (QSPLIT=8).
// grid (SK/64, Bsz, QSPLIT), 256 threads, 4q x 4s per thread.
// ---------------------------------------------------------------------------
__global__ __launch_bounds__(256) void k_colsum(
    const float* __restrict__ wsQ, const float* __restrict__ wsK,
    const int* __restrict__ mask, float* __restrict__ part)
{
    __shared__ float kT[64][68];   // [d][s]
    __shared__ float qT[64][68];   // [d][q]

    const int t = threadIdx.x;
    const int tx = t & 15, ty = t >> 4;
    const int s0 = blockIdx.x * 64;
    const int b  = blockIdx.y;
    const int qs = blockIdx.z;
    const float* Qb = wsQ + (size_t)b * SQ * DKk;
    const float* Kb = wsK + (size_t)b * SK * DKk;

    // stage K tile once (transposed)
#pragma unroll
    for (int i = 0; i < 4; ++i) {
        const int flat = t + 256 * i;          // 0..1023
        const int s = flat >> 4, d4 = flat & 15;
        const float4 v = *(const float4*)(Kb + (size_t)(s0 + s) * DKk + 4 * d4);
        kT[4 * d4 + 0][s] = v.x; kT[4 * d4 + 1][s] = v.y;
        kT[4 * d4 + 2][s] = v.z; kT[4 * d4 + 3][s] = v.w;
    }

    float cs[4] = {0.0f, 0.0f, 0.0f, 0.0f};
    const int qbase = qs * (SQ / QSPLIT);

    for (int qt = 0; qt < SQ / QSPLIT; qt += 64) {
        const int q0 = qbase + qt;
#pragma unroll
        for (int i = 0; i < 4; ++i) {
            const int flat = t + 256 * i;
            const int q = flat >> 4, d4 = flat & 15;
            const float4 v = *(const float4*)(Qb + (size_t)(q0 + q) * DKk + 4 * d4);
            qT[4 * d4 + 0][q] = v.x; qT[4 * d4 + 1][q] = v.y;
            qT[4 * d4 + 2][q] = v.z; qT[4 * d4 + 3][q] = v.w;
        }
        __syncthreads();

        float acc[4][4];
#pragma unroll
        for (int i = 0; i < 4; ++i)
#pragma unroll
            for (int j = 0; j < 4; ++j) acc[i][j] = 0.0f;

#pragma unroll 16
        for (int d = 0; d < 64; ++d) {
            const float4 qa = *(const float4*)&qT[d][4 * ty];
            const float4 ka = *(const float4*)&kT[d][4 * tx];
            fma_4x4(acc, qa, ka);
        }

#pragma unroll
        for (int i = 0; i < 4; ++i) {
            const int qg = q0 + 4 * ty + i;
            const int4 mk = *(const int4*)(mask + ((size_t)b * SQ + qg) * SK + s0 + 4 * tx);
            cs[0] += mk.x ? __expf(acc[i][0]) : 0.0f;
            cs[1] += mk.y ? __expf(acc[i][1]) : 0.0f;
            cs[2] += mk.z ? __expf(acc[i][2]) : 0.0f;
            cs[3] += mk.w ? __expf(acc[i][3]) : 0.0f;
        }
        __syncthreads();
    }

    // reduce over ty: first within wave (ty spans 4 values per wave)...
#pragma unroll
    for (int j = 0; j < 4; ++j) {
        cs[j] += __shfl_xor(cs[j], 16);
        cs[j] += __shfl_xor(cs[j], 32);
    }
    // ...then across the 4 waves via LDS (reuse qT space; safe after loop's sync)
    float* red = &qT[0][0];
    const int lane = t & 63, w = t >> 6;
    if (lane < 16) {
        *(float4*)(red + w * 64 + 4 * tx) = make_float4(cs[0], cs[1], cs[2], cs[3]);
    }
    __syncthreads();
    if (t < 64) {
        const float sum = red[t] + red[64 + t] + red[128 + t] + red[192 + t];
        part[(size_t)qs * (Bsz * SK) + (size_t)b * SK + s0 + t] = sum;
    }
}

// K2b: linv[i] = 1 / sum_js part[js][i].  grid (Bsz*SK/256)
__global__ void k_linv(const float* __restrict__ part, float* __restrict__ linv)
{
    const int i = blockIdx.x * 256 + threadIdx.x;
    float s = 0.0f;
#pragma unroll
    for (int j = 0; j < QSPLIT; ++j) s += part[(size_t)j * (Bsz * SK) + i];
    linv[i] = 1.0f / s;
}

// ---------------------------------------------------------------------------
// K3: y_part[q,k] = sum_s (mask * exp(S[q,s])) * (V[s,k] * linv[s]).
// Block: 64 q-rows x all 64 k-dims, iterates s in tiles of 64 over half the
// s-range (SSPLIT=2). 256 threads; S-GEMM 4qx4s/thread, y-GEMM 4qx4k/thread.
// grid (SQ/64, Bsz, SSPLIT)
// ---------------------------------------------------------------------------
__global__ __launch_bounds__(256) void k_attn(
    const float* __restrict__ wsQ, const float* __restrict__ wsK, const float* __restrict__ wsV,
    const float* __restrict__ linv, const int* __restrict__ mask,
    float* __restrict__ ypart)
{
    __shared__ float qT[64][64];   // [d][q]  staged once; reads are 4-addr broadcast
    __shared__ float kT[64][68];   // [d][s]
    __shared__ float vL[64][64];   // [s][k]  (V * linv)
    __shared__ float pT[64][68];   // [s][q]

    const int t = threadIdx.x;
    const int tx = t & 15, ty = t >> 4;
    const int q0 = blockIdx.x * 64;
    const int b  = blockIdx.y;
    const int sz = blockIdx.z;
    const float* Qb = wsQ + (size_t)b * SQ * DKk;
    const float* Kb = wsK + (size_t)b * SK * DKk;
    const float* Vb = wsV + (size_t)b * SK * DKk;
    const float* lb = linv + (size_t)b * SK;

    // stage qT once (transposed)
#pragma unroll
    for (int i = 0; i < 4; ++i) {
        const int flat = t + 256 * i;
        const int q = flat >> 4, d4 = flat & 15;
        const float4 v = *(const float4*)(Qb + (size_t)(q0 + q) * DKk + 4 * d4);
        qT[4 * d4 + 0][q] = v.x; qT[4 * d4 + 1][q] = v.y;
        qT[4 * d4 + 2][q] = v.z; qT[4 * d4 + 3][q] = v.w;
    }

    float yacc[4][4];
#pragma unroll
    for (int i = 0; i < 4; ++i)
#pragma unroll
        for (int j = 0; j < 4; ++j) yacc[i][j] = 0.0f;

    const int sbase = sz * (SK / SSPLIT);

    for (int st = 0; st < SK / SSPLIT; st += 64) {
        const int s0 = sbase + st;
        __syncthreads();   // prev y-GEMM (and iter-0 qT staging) complete
        // stage kT (transposed) and vL (row-major, scaled by linv)
#pragma unroll
        for (int i = 0; i < 4; ++i) {
            const int flat = t + 256 * i;
            const int s = flat >> 4, d4 = flat & 15;
            const float4 v = *(const float4*)(Kb + (size_t)(s0 + s) * DKk + 4 * d4);
            kT[4 * d4 + 0][s] = v.x; kT[4 * d4 + 1][s] = v.y;
            kT[4 * d4 + 2][s] = v.z; kT[4 * d4 + 3][s] = v.w;
        }
#pragma unroll
        for (int i = 0; i < 4; ++i) {
            const int flat = t + 256 * i;
            const int s = flat >> 4, k4 = flat & 15;
            const float4 v = *(const float4*)(Vb + (size_t)(s0 + s) * DKk + 4 * k4);
            const float li = lb[s0 + s];
            vL[s][4 * k4 + 0] = v.x * li; vL[s][4 * k4 + 1] = v.y * li;
            vL[s][4 * k4 + 2] = v.z * li; vL[s][4 * k4 + 3] = v.w * li;
        }
        __syncthreads();

        // S-GEMM
        float acc[4][4];
#pragma unroll
        for (int i = 0; i < 4; ++i)
#pragma unroll
            for (int j = 0; j < 4; ++j) acc[i][j] = 0.0f;
#pragma unroll 16
        for (int d = 0; d < 64; ++d) {
            const float4 qa = *(const float4*)&qT[d][4 * ty];
            const float4 ka = *(const float4*)&kT[d][4 * tx];
            fma_4x4(acc, qa, ka);
        }

        // mask + exp -> P
        float p[4][4];
#pragma unroll
        for (int i = 0; i < 4; ++i) {
            const int qg = q0 + 4 * ty + i;
            const int4 mk = *(const int4*)(mask + ((size_t)b * SQ + qg) * SK + s0 + 4 * tx);
            p[i][0] = mk.x ? __expf(acc[i][0]) : 0.0f;
            p[i][1] = mk.y ? __expf(acc[i][1]) : 0.0f;
            p[i][2] = mk.z ? __expf(acc[i][2]) : 0.0f;
            p[i][3] = mk.w ? __expf(acc[i][3]) : 0.0f;
        }
        // write P transposed: pT[s][q]
#pragma unroll
        for (int j = 0; j < 4; ++j) {
            *(float4*)&pT[4 * tx + j][4 * ty] = make_float4(p[0][j], p[1][j], p[2][j], p[3][j]);
        }
        __syncthreads();

        // y-GEMM: yacc += P^T-tile x vL
#pragma unroll 16
        for (int ss = 0; ss < 64; ++ss) {
            const float4 pa = *(const float4*)&pT[ss][4 * ty];
            const float4 va = *(const float4*)&vL[ss][4 * tx];
            fma_4x4(yacc, pa, va);
        }
    }

#pragma unroll
    for (int i = 0; i < 4; ++i) {
        const size_t row = (size_t)b * SQ + q0 + 4 * ty + i;
        *(float4*)(ypart + (size_t)sz * (Bsz * SQ * DKk) + row * DKk + 4 * tx) =
            make_float4(yacc[i][0], yacc[i][1], yacc[i][2], yacc[i][3]);
    }
}

// K4: y = ypart[0] + ypart[1].  grid (Bsz*SQ*DKk/4/256)
__global__ void k_reduce(const float* __restrict__ ypart, float* __restrict__ out)
{
    const int i = blockIdx.x * 256 + threadIdx.x;  // float4 index
    const float4 a = ((const float4*)ypart)[i];
    const float4 c = ((const float4*)(ypart + (size_t)Bsz * SQ * DKk))[i];
    ((float4*)out)[i] = make_float4(a.x + c.x, a.y + c.y, a.z + c.z, a.w + c.w);
}

// ---------------------------------------------------------------------------
extern "C" void kernel_launch(void* const* d_in, const int* in_sizes, int n_in,
                              void* d_out, int out_size, void* d_ws, size_t ws_size,
                              hipStream_t stream)
{
    (void)in_sizes; (void)n_in; (void)out_size; (void)ws_size;
    const float* xq = (const float*)d_in[0];
    const float* xk = (const float*)d_in[1];
    const float* xv = (const float*)d_in[2];
    const int*  mask = (const int*)d_in[3];
    const float* Wq = (const float*)d_in[4];
    const float* bq = (const float*)d_in[5];
    const float* Wk = (const float*)d_in[6];
    const float* bk = (const float*)d_in[7];
    const float* Wv = (const float*)d_in[8];
    const float* bv = (const float*)d_in[9];
    float* out = (float*)d_out;
    float* ws  = (float*)d_ws;   // needs ~21.6 MiB

    k_proj<<<dim3((Bsz * SQ) / 128, 3), dim3(128), 0, stream>>>(
        xq, xk, xv, Wq, bq, Wk, bk, Wv, bv, ws);
    k_colsum<<<dim3(SK / 64, Bsz, QSPLIT), dim3(256), 0, stream>>>(
        ws + OFF_Q, ws + OFF_K, mask, ws + OFF_PL);
    k_linv<<<dim3((Bsz * SK) / 256), dim3(256), 0, stream>>>(ws + OFF_PL, ws + OFF_LI);
    k_attn<<<dim3(SQ / 64, Bsz, SSPLIT), dim3(256), 0, stream>>>(
        ws + OFF_Q, ws + OFF_K, ws + OFF_V, ws + OFF_LI, mask, ws + OFF_YP);
    k_reduce<<<dim3((Bsz * SQ * DKk / 4) / 256), dim3(256), 0, stream>>>(ws + OFF_YP, out);
}

// Round 3
// 633.906 us; speedup vs baseline: 1.5440x; 1.5440x over previous
//
#include <hip/hip_runtime.h>
#include <hip/hip_bf16.h>

#define Bsz 4
#define SQ 4096
#define SK 4096
#define DMODEL 1024
#define DKk 64
#define QSPLIT 8

typedef __attribute__((ext_vector_type(8))) short bf8_t;
typedef __attribute__((ext_vector_type(4))) float f4_t;

#define MFMA(a, b, c) __builtin_amdgcn_mfma_f32_16x16x32_bf16((a), (b), (c), 0, 0, 0)

// Workspace byte offsets. Total = 16.5625 MiB + 64 KiB (< 20.6 MiB proven available).
#define OFF_Q    ((size_t)0)            // bf16 [B*SQ][64]   2 MiB
#define OFF_K    ((size_t)(2u << 20))   // bf16 [B*SK][64]   2 MiB
#define OFF_V    ((size_t)(4u << 20))   // bf16 [B*SK][64]   2 MiB
#define OFF_VT   ((size_t)(6u << 20))   // bf16 [B][64][SK]  2 MiB (V*linv, transposed)
#define OFF_BITS ((size_t)(8u << 20))   // u32  [B*SQ][128]  8 MiB
#define OFF_PART ((size_t)(16u << 20))  // f32  [QSPLIT][B][SK] 512 KiB
#define OFF_LINV (OFF_PART + (512u << 10)) // f32 [B][SK] 64 KiB

__device__ __forceinline__ short f2bf(float f) {
    union { float f; unsigned u; } v; v.f = f;
    return (short)((v.u + 0x7FFFu + ((v.u >> 16) & 1u)) >> 16);
}
__device__ __forceinline__ float bf2f(short h) {
    union { unsigned u; float f; } v; v.u = ((unsigned)(unsigned short)h) << 16;
    return v.f;
}
__device__ __forceinline__ bf8_t cvt8(float4 a, float4 b) {
    union { __hip_bfloat162 h[4]; bf8_t v; } u;
    u.h[0] = __float22bfloat162_rn(float2{a.x, a.y});
    u.h[1] = __float22bfloat162_rn(float2{a.z, a.w});
    u.h[2] = __float22bfloat162_rn(float2{b.x, b.y});
    u.h[3] = __float22bfloat162_rn(float2{b.z, b.w});
    return u.v;
}

// ---------------------------------------------------------------------------
// K1: QKV projection via MFMA. out = bf16((x @ W^T + b) * scale).
// MFMA 16x16x32 bf16: A-frag lane l: row=l&15, k=(l>>4)*8..+7 (contiguous);
// B-frag lane l: col=l&15, k=(l>>4)*8..+7 -> W[n][k] rows directly.
// Block 256 thr = 4 waves x 32 rows; grid (16384/128, 3).
// ---------------------------------------------------------------------------
__global__ __launch_bounds__(256) void k_proj(
    const float* __restrict__ xq, const float* __restrict__ xk, const float* __restrict__ xv,
    const float* __restrict__ Wq, const float* __restrict__ bq,
    const float* __restrict__ Wk, const float* __restrict__ bk,
    const float* __restrict__ Wv, const float* __restrict__ bv,
    char* __restrict__ ws)
{
    const int t = threadIdx.x, l = t & 63, w = t >> 6;
    const int l15 = l & 15, g = l >> 4;
    const int which = blockIdx.y;
    const float* x    = which == 0 ? xq : (which == 1 ? xk : xv);
    const float* W    = which == 0 ? Wq : (which == 1 ? Wk : Wv);
    const float* bias = which == 0 ? bq : (which == 1 ? bk : bv);
    short* out = (short*)(ws + (which == 0 ? OFF_Q : (which == 1 ? OFF_K : OFF_V)));
    const float scale = (which == 0) ? 0.125f : 1.0f;

    const int row0 = blockIdx.x * 128 + w * 32;

    f4_t acc[2][4];
#pragma unroll
    for (int m = 0; m < 2; ++m)
#pragma unroll
        for (int n = 0; n < 4; ++n) acc[m][n] = f4_t{0.f, 0.f, 0.f, 0.f};

    for (int kc = 0; kc < DMODEL; kc += 32) {
        bf8_t af[2], bfg[4];
#pragma unroll
        for (int m = 0; m < 2; ++m) {
            const float* p = x + (size_t)(row0 + m * 16 + l15) * DMODEL + kc + g * 8;
            af[m] = cvt8(*(const float4*)p, *(const float4*)(p + 4));
        }
#pragma unroll
        for (int n = 0; n < 4; ++n) {
            const float* p = W + (size_t)(n * 16 + l15) * DMODEL + kc + g * 8;
            bfg[n] = cvt8(*(const float4*)p, *(const float4*)(p + 4));
        }
#pragma unroll
        for (int m = 0; m < 2; ++m)
#pragma unroll
            for (int n = 0; n < 4; ++n) acc[m][n] = MFMA(af[m], bfg[n], acc[m][n]);
    }

#pragma unroll
    for (int n = 0; n < 4; ++n) {
        const float bb = bias[n * 16 + l15];
#pragma unroll
        for (int m = 0; m < 2; ++m)
#pragma unroll
            for (int i = 0; i < 4; ++i) {
                const int row = row0 + m * 16 + g * 4 + i;
                out[(size_t)row * DKk + n * 16 + l15] = f2bf((acc[m][n][i] + bb) * scale);
            }
    }
}

// ---------------------------------------------------------------------------
// K2: mask int32 -> bitmask. bit i of word = (mask[32w+i] != 0).
// ---------------------------------------------------------------------------
__global__ __launch_bounds__(256) void k_pack(const int* __restrict__ m,
                                              unsigned long long* __restrict__ bits)
{
    const int lane = threadIdx.x & 63;
    const long long nW = (long long)gridDim.x * 4;
    const long long N = (long long)Bsz * SQ * SK;
    long long wid = (long long)blockIdx.x * 4 + (threadIdx.x >> 6);
    for (long long base = wid * 256; base < N; base += nW * 256) {
        unsigned long long b0 = __ballot(m[base + lane] != 0);
        unsigned long long b1 = __ballot(m[base + 64 + lane] != 0);
        unsigned long long b2 = __ballot(m[base + 128 + lane] != 0);
        unsigned long long b3 = __ballot(m[base + 192 + lane] != 0);
        if (lane < 4) {
            unsigned long long v = lane == 0 ? b0 : (lane == 1 ? b1 : (lane == 2 ? b2 : b3));
            bits[base / 64 + lane] = v;
        }
    }
}

// ---------------------------------------------------------------------------
// K3: column sums l[s] = sum_q bit * exp(S[q,s]), S via MFMA (Q prescaled).
// grid (SK/128, B, QSPLIT); 4 waves, each wave: 32 s-cols x 512 q.
// C-layout: col = lane&15, row = (lane>>4)*4 + reg.
// ---------------------------------------------------------------------------
__global__ __launch_bounds__(256) void k_colsum(
    const short* __restrict__ Q, const short* __restrict__ K,
    const unsigned* __restrict__ bits, float* __restrict__ part)
{
    const int t = threadIdx.x, l = t & 63, w = t >> 6;
    const int l15 = l & 15, g = l >> 4;
    const int b = blockIdx.y, qs = blockIdx.z;
    const int sw = blockIdx.x * 128 + w * 32;

    bf8_t kb[2][2];
#pragma unroll
    for (int n = 0; n < 2; ++n)
#pragma unroll
        for (int ks = 0; ks < 2; ++ks)
            kb[n][ks] = *(const bf8_t*)(K + (size_t)(b * SK + sw + n * 16 + l15) * DKk + ks * 32 + g * 8);

    float cs0 = 0.f, cs1 = 0.f;
    const int q0b = qs * (SQ / QSPLIT);

    for (int qt = 0; qt < SQ / QSPLIT; qt += 64) {
        bf8_t qa[4][2];
#pragma unroll
        for (int m = 0; m < 4; ++m)
#pragma unroll
            for (int ks = 0; ks < 2; ++ks)
                qa[m][ks] = *(const bf8_t*)(Q + (size_t)(b * SQ + q0b + qt + m * 16 + l15) * DKk + ks * 32 + g * 8);

#pragma unroll
        for (int m = 0; m < 4; ++m) {
            f4_t a0 = {0.f, 0.f, 0.f, 0.f}, a1 = {0.f, 0.f, 0.f, 0.f};
            a0 = MFMA(qa[m][0], kb[0][0], a0);
            a0 = MFMA(qa[m][1], kb[0][1], a0);
            a1 = MFMA(qa[m][0], kb[1][0], a1);
            a1 = MFMA(qa[m][1], kb[1][1], a1);
            const int qr = q0b + qt + m * 16 + g * 4;
#pragma unroll
            for (int i = 0; i < 4; ++i) {
                const unsigned word = bits[(size_t)(b * SQ + qr + i) * 128 + (sw >> 5)];
                if ((word >> l15) & 1u)        cs0 += __expf(a0[i]);
                if ((word >> (16 + l15)) & 1u) cs1 += __expf(a1[i]);
            }
        }
    }

    cs0 += __shfl_xor(cs0, 16); cs0 += __shfl_xor(cs0, 32);
    cs1 += __shfl_xor(cs1, 16); cs1 += __shfl_xor(cs1, 32);
    if (l < 16) {
        float* p = part + (size_t)(qs * Bsz + b) * SK + sw;
        p[l15]      = cs0;
        p[16 + l15] = cs1;
    }
}

// K3b: linv = 1 / sum of partials. grid (B*SK/256)
__global__ void k_linv(const float* __restrict__ part, float* __restrict__ linv)
{
    const int i = blockIdx.x * 256 + threadIdx.x;
    float s = 0.f;
#pragma unroll
    for (int j = 0; j < QSPLIT; ++j) s += part[(size_t)j * (Bsz * SK) + i];
    linv[i] = 1.0f / s;
}

// K4: Vt[b][n][s] = bf16(V[b][s][n] * linv[b][s]).  grid (B*SK*8/256)
__global__ void k_vscale(const short* __restrict__ V, const float* __restrict__ linv,
                         short* __restrict__ Vt)
{
    const int tg = blockIdx.x * 256 + threadIdx.x;   // 131072 threads
    const int b = tg >> 15, rem = tg & 32767;
    const int nch = rem >> 12, s = rem & 4095;
    const float li = linv[b * SK + s];
    union { short s[8]; bf8_t v; } u;
    u.v = *(const bf8_t*)(V + (size_t)(b * SK + s) * DKk + nch * 8);
#pragma unroll
    for (int j = 0; j < 8; ++j)
        Vt[(size_t)(b * DKk + nch * 8 + j) * SK + s] = f2bf(bf2f(u.s[j]) * li);
}

// ---------------------------------------------------------------------------
// K5: y[q,k] = sum_s (bit*exp(S)) * Vt[k][s]. Block = 32 q, 4 waves:
// (qsub = w>>1) x (s-half = w&1). Per s-tile(128): S-MFMA -> P(bf16, wave-
// private LDS, pitch 136) -> PV-MFMA from P + shared Vt tile. Cross-half
// reduce via LDS, direct fp32 store. grid (SQ/32, B).
// ---------------------------------------------------------------------------
__global__ __launch_bounds__(256) void k_attn(
    const short* __restrict__ Q, const short* __restrict__ K, const short* __restrict__ Vt,
    const unsigned* __restrict__ bits, float* __restrict__ out)
{
    __shared__ __align__(16) short VtL[2][64 * 136];   // [s-half tile][n][s] 34816 B
    __shared__ __align__(16) short Pl[4][16 * 136];    // per-wave P          17408 B
    __shared__ __align__(16) float yred[2][1024];      // cross-half reduce    8192 B

    const int t = threadIdx.x, l = t & 63, w = t >> 6;
    const int l15 = l & 15, g = l >> 4;
    const int b = blockIdx.y;
    const int qsub = w >> 1, sh = w & 1;
    const int qw = blockIdx.x * 32 + qsub * 16;

    bf8_t qa[2];
#pragma unroll
    for (int ks = 0; ks < 2; ++ks)
        qa[ks] = *(const bf8_t*)(Q + (size_t)(b * SQ + qw + l15) * DKk + ks * 32 + g * 8);

    f4_t acc[4];
#pragma unroll
    for (int n = 0; n < 4; ++n) acc[n] = f4_t{0.f, 0.f, 0.f, 0.f};

    for (int tile = 0; tile < 16; ++tile) {
        const int sBase = sh * 2048 + tile * 128;
        __syncthreads();   // prior PV reads of VtL done
        // stage both halves' Vt tiles (64 n x 128 s each)
#pragma unroll
        for (int it = 0; it < 8; ++it) {
            const int flat = t + 256 * it;             // 0..2047
            const int half = flat >> 10, n = (flat >> 4) & 63, ch = flat & 15;
            const int s = half * 2048 + tile * 128 + ch * 8;
            *(bf8_t*)&VtL[half][n * 136 + ch * 8] =
                *(const bf8_t*)(Vt + (size_t)(b * DKk + n) * SK + s);
        }
        __syncthreads();

        uint4 mw[4];
#pragma unroll
        for (int i = 0; i < 4; ++i)
            mw[i] = *(const uint4*)(bits + (size_t)(b * SQ + qw + g * 4 + i) * 128 + (sBase >> 5));

        // S + mask + exp -> P (wave-private, no barrier needed)
#pragma unroll
        for (int nt = 0; nt < 8; ++nt) {
            f4_t s4 = {0.f, 0.f, 0.f, 0.f};
            const short* kp = K + (size_t)(b * SK + sBase + nt * 16 + l15) * DKk + g * 8;
            s4 = MFMA(qa[0], *(const bf8_t*)kp, s4);
            s4 = MFMA(qa[1], *(const bf8_t*)(kp + 32), s4);
            const int wi = nt >> 1, bp = (nt & 1) * 16 + l15;
#pragma unroll
            for (int i = 0; i < 4; ++i) {
                const unsigned word = ((const unsigned*)&mw[i])[wi];
                const float p = ((word >> bp) & 1u) ? __expf(s4[i]) : 0.0f;
                Pl[w][(g * 4 + i) * 136 + nt * 16 + l15] = f2bf(p);
            }
        }

        // PV: acc[n] += P(16q x 128s) x Vl(128s x 64k)
#pragma unroll
        for (int ks2 = 0; ks2 < 4; ++ks2) {
            const bf8_t pa = *(const bf8_t*)&Pl[w][l15 * 136 + ks2 * 32 + g * 8];
#pragma unroll
            for (int n = 0; n < 4; ++n) {
                const bf8_t vb = *(const bf8_t*)&VtL[sh][(n * 16 + l15) * 136 + ks2 * 32 + g * 8];
                acc[n] = MFMA(pa, vb, acc[n]);
            }
        }
    }

    // cross-half reduce + store
    __syncthreads();
    if (sh == 1) {
#pragma unroll
        for (int n = 0; n < 4; ++n) *(f4_t*)&yred[qsub][l * 16 + n * 4] = acc[n];
    }
    __syncthreads();
    if (sh == 0) {
#pragma unroll
        for (int n = 0; n < 4; ++n) {
            const f4_t o = *(const f4_t*)&yred[qsub][l * 16 + n * 4];
#pragma unroll
            for (int i = 0; i < 4; ++i)
                out[(size_t)(b * SQ + qw + g * 4 + i) * DKk + n * 16 + l15] = acc[n][i] + o[i];
        }
    }
}

// ---------------------------------------------------------------------------
extern "C" void kernel_launch(void* const* d_in, const int* in_sizes, int n_in,
                              void* d_out, int out_size, void* d_ws, size_t ws_size,
                              hipStream_t stream)
{
    (void)in_sizes; (void)n_in; (void)out_size; (void)ws_size;
    const float* xq = (const float*)d_in[0];
    const float* xk = (const float*)d_in[1];
    const float* xv = (const float*)d_in[2];
    const int*  mask = (const int*)d_in[3];
    const float* Wq = (const float*)d_in[4];
    const float* bq = (const float*)d_in[5];
    const float* Wk = (const float*)d_in[6];
    const float* bk = (const float*)d_in[7];
    const float* Wv = (const float*)d_in[8];
    const float* bv = (const float*)d_in[9];
    float* out = (float*)d_out;
    char* ws = (char*)d_ws;

    short*    Q    = (short*)(ws + OFF_Q);
    short*    Kk   = (short*)(ws + OFF_K);
    short*    V    = (short*)(ws + OFF_V);
    short*    Vt   = (short*)(ws + OFF_VT);
    unsigned* bits = (unsigned*)(ws + OFF_BITS);
    float*    part = (float*)(ws + OFF_PART);
    float*    linv = (float*)(ws + OFF_LINV);

    k_proj<<<dim3(128, 3), dim3(256), 0, stream>>>(xq, xk, xv, Wq, bq, Wk, bk, Wv, bv, ws);
    k_pack<<<dim3(2048), dim3(256), 0, stream>>>(mask, (unsigned long long*)bits);
    k_colsum<<<dim3(SK / 128, Bsz, QSPLIT), dim3(256), 0, stream>>>(Q, Kk, bits, part);
    k_linv<<<dim3((Bsz * SK) / 256), dim3(256), 0, stream>>>(part, linv);
    k_vscale<<<dim3((Bsz * SK * 8) / 256), dim3(256), 0, stream>>>(V, linv, Vt);
    k_attn<<<dim3(SQ / 32, Bsz), dim3(256), 0, stream>>>(Q, Kk, Vt, bits, out);
}